// Round 1
// baseline (265.806 us; speedup 1.0000x reference)
//
#include <hip/hip_runtime.h>
#include <cstdint>
#include <cstddef>

typedef __attribute__((ext_vector_type(8))) short bf16x8;
typedef __attribute__((ext_vector_type(4))) float f32x4;

__device__ __forceinline__ unsigned short f2bf(float f) {
  unsigned int u = __builtin_bit_cast(unsigned int, f);
  u += 0x7FFFu + ((u >> 16) & 1u);
  return (unsigned short)(u >> 16);
}
__device__ __forceinline__ float bf2f(unsigned short h) {
  unsigned int u = ((unsigned int)h) << 16;
  return __builtin_bit_cast(float, u);
}

// ---------------- fp32 -> bf16 convert (x) ----------------
__global__ void k_convert(const float* __restrict__ in, unsigned short* __restrict__ out, int n4) {
  int i = blockIdx.x * blockDim.x + threadIdx.x;
  if (i >= n4) return;
  float4 v = reinterpret_cast<const float4*>(in)[i];
  uint2 o;
  o.x = (unsigned int)f2bf(v.x) | ((unsigned int)f2bf(v.y) << 16);
  o.y = (unsigned int)f2bf(v.z) | ((unsigned int)f2bf(v.w) << 16);
  reinterpret_cast<uint2*>(out)[i] = o;
}

// ---------------- transpose + convert W [K][N] fp32 -> [N][K] bf16 ----------------
__global__ void k_wtrans(const float* __restrict__ in, unsigned short* __restrict__ out,
                         int rows, int cols) {
  __shared__ float tile[32][33];
  int c0 = blockIdx.x * 32, r0 = blockIdx.y * 32;
  int tx = threadIdx.x, ty = threadIdx.y;
#pragma unroll
  for (int j = 0; j < 4; j++)
    tile[ty + j * 8][tx] = in[(size_t)(r0 + ty + j * 8) * cols + c0 + tx];
  __syncthreads();
#pragma unroll
  for (int j = 0; j < 4; j++)
    out[(size_t)(c0 + ty + j * 8) * rows + r0 + tx] = f2bf(tile[tx][ty + j * 8]);
}

// ---------------- RoPE cos/sin tables [2048][32] ----------------
__global__ void k_rope_tab(float* __restrict__ ct, float* __restrict__ st) {
  int i = blockIdx.x * blockDim.x + threadIdx.x;  // t*32 + j
  int t = i >> 5, j = i & 31;
  float invf = __powf(10000.0f, -(float)j / 32.0f);
  float ang = (float)t * invf;
  ct[i] = cosf(ang);
  st[i] = sinf(ang);
}

// ---------------- bf16 MFMA GEMM: C[M][N] = A[M][K] * Bt[N][K]^T ----------------
// 128x128 tile, BK=32, 4 waves (2x2), 4x4 16x16x32 frags per wave.
template<int OUT_BF16>
__global__ void k_gemm(const unsigned short* __restrict__ A,
                       const unsigned short* __restrict__ Bt,
                       void* __restrict__ C, int M, int N, int K) {
  __shared__ unsigned short Ta[128 * 32];
  __shared__ unsigned short Tb[128 * 32];
  const int tid = threadIdx.x;
  const int m0 = blockIdx.y * 128, n0 = blockIdx.x * 128;
  const int w = tid >> 6, l = tid & 63;
  const int lr = l & 15, lg = l >> 4;
  const int wm = (w >> 1) * 64, wn = (w & 1) * 64;
  const int srow = tid >> 1, scol = (tid & 1) * 16;
  f32x4 acc[4][4] = {};
  for (int k0 = 0; k0 < K; k0 += 32) {
    uint4 a0 = *(const uint4*)&A[(size_t)(m0 + srow) * K + k0 + scol];
    uint4 a1 = *(const uint4*)&A[(size_t)(m0 + srow) * K + k0 + scol + 8];
    uint4 b0 = *(const uint4*)&Bt[(size_t)(n0 + srow) * K + k0 + scol];
    uint4 b1 = *(const uint4*)&Bt[(size_t)(n0 + srow) * K + k0 + scol + 8];
    __syncthreads();
    *(uint4*)&Ta[srow * 32 + scol] = a0;
    *(uint4*)&Ta[srow * 32 + scol + 8] = a1;
    *(uint4*)&Tb[srow * 32 + scol] = b0;
    *(uint4*)&Tb[srow * 32 + scol + 8] = b1;
    __syncthreads();
    bf16x8 af[4], bfr[4];
#pragma unroll
    for (int i = 0; i < 4; i++)
      af[i] = *(const bf16x8*)&Ta[(wm + i * 16 + lr) * 32 + lg * 8];
#pragma unroll
    for (int j = 0; j < 4; j++)
      bfr[j] = *(const bf16x8*)&Tb[(wn + j * 16 + lr) * 32 + lg * 8];
#pragma unroll
    for (int i = 0; i < 4; i++)
#pragma unroll
      for (int j = 0; j < 4; j++)
        acc[i][j] = __builtin_amdgcn_mfma_f32_16x16x32_bf16(af[i], bfr[j], acc[i][j], 0, 0, 0);
  }
#pragma unroll
  for (int i = 0; i < 4; i++)
#pragma unroll
    for (int j = 0; j < 4; j++)
#pragma unroll
      for (int r = 0; r < 4; r++) {
        int gm = m0 + wm + i * 16 + lg * 4 + r;
        int gn = n0 + wn + j * 16 + lr;
        float v = acc[i][j][r];
        if (OUT_BF16) ((unsigned short*)C)[(size_t)gm * N + gn] = f2bf(v);
        else          ((float*)C)[(size_t)gm * N + gn] = v;
      }
}

// ---------------- RoPE + split qkv -> qh (scaled 1/8), kh  [B,H,T,D] bf16 ----------------
__global__ void k_rope_split(const unsigned short* __restrict__ qkv,
                             const float* __restrict__ ct, const float* __restrict__ st,
                             unsigned short* __restrict__ qh, unsigned short* __restrict__ kh) {
  int idx = blockIdx.x * blockDim.x + threadIdx.x;  // m*1024 + c
  int m = idx >> 10, c = idx & 1023;
  int t = m & 2047, b = m >> 11;
  int h = c >> 6, d = c & 63;
  int j = d & 31;
  float cs = ct[t * 32 + j], sn = st[t * 32 + j];
  size_t rowb = (size_t)m * 3072;
  float qv = bf2f(qkv[rowb + c]);
  float qo = bf2f(qkv[rowb + h * 64 + (d ^ 32)]);
  float kv = bf2f(qkv[rowb + 1024 + c]);
  float ko = bf2f(qkv[rowb + 1024 + h * 64 + (d ^ 32)]);
  float sgn = (d < 32) ? -1.0f : 1.0f;
  float qr = qv * cs + sgn * qo * sn;
  float kr = kv * cs + sgn * ko * sn;
  int bh = b * 16 + h;
  qh[(size_t)(bh * 2048 + t) * 64 + d] = f2bf(qr * 0.125f);
  kh[(size_t)(bh * 2048 + t) * 64 + d] = f2bf(kr);
}

// ---------------- V transpose: qkv v-part [m][c] -> vt [B,H,D,T] bf16 ----------------
__global__ void k_vtrans(const unsigned short* __restrict__ qkv, unsigned short* __restrict__ vt) {
  __shared__ unsigned short tile[64][72];
  const int bh = blockIdx.y, b = bh >> 4, h = bh & 15;
  const int t0 = blockIdx.x * 64;
  const int tid = threadIdx.x;
  {
    int r = tid >> 2, c = (tid & 3) * 16;
    const unsigned short* src = &qkv[(size_t)(b * 2048 + t0 + r) * 3072 + 2048 + h * 64 + c];
    uint4 v0 = *(const uint4*)src;
    uint4 v1 = *(const uint4*)(src + 8);
    *(uint4*)&tile[r][c] = v0;
    *(uint4*)&tile[r][c + 8] = v1;
  }
  __syncthreads();
#pragma unroll
  for (int q = 0; q < 2; q++) {
    int d = (tid >> 3) + q * 32;
    int tts = (tid & 7) * 8;
    unsigned short vals[8];
#pragma unroll
    for (int e = 0; e < 8; e++) vals[e] = tile[tts + e][d];
    *(uint4*)&vt[((size_t)bh * 64 + d) * 2048 + t0 + tts] = *(uint4*)vals;
  }
}

// ---------------- causal flash attention ----------------
// grid (T/64, B*H), 256 threads = 4 waves; wave w owns Q rows [q0+16w, q0+16w+16).
// KV blocks of 32; K tile [32][64], V tile (transposed) [64][32] in LDS.
__global__ void k_attn(const unsigned short* __restrict__ qh,
                       const unsigned short* __restrict__ kh,
                       const unsigned short* __restrict__ vt,
                       unsigned short* __restrict__ att) {
  __shared__ unsigned short Kl[32 * 64];
  __shared__ unsigned short Vl[64 * 32];
  __shared__ unsigned short Pl[4][16 * 32];
  const int bh = blockIdx.y, b = bh >> 4, h = bh & 15;
  const int q0 = blockIdx.x * 64;
  const int tid = threadIdx.x;
  const int w = tid >> 6, l = tid & 63;
  const int lr = l & 15, lg = l >> 4;
  const unsigned short* qbase = qh + (size_t)bh * 2048 * 64;
  const unsigned short* kbase = kh + (size_t)bh * 2048 * 64;
  const unsigned short* vbase = vt + (size_t)bh * 64 * 2048;

  const int qrow = q0 + w * 16 + lr;
  bf16x8 qf0 = *(const bf16x8*)&qbase[(size_t)qrow * 64 + lg * 8];
  bf16x8 qf1 = *(const bf16x8*)&qbase[(size_t)qrow * 64 + 32 + lg * 8];

  float mrun[4], lrun[4];
  f32x4 of[4] = {};
#pragma unroll
  for (int r = 0; r < 4; r++) { mrun[r] = -3.0e38f; lrun[r] = 0.0f; }

  const int nkv = (q0 >> 5) + 2;
  const int wqmin = q0 + w * 16;
  const int wqmax = wqmin + 15;
  for (int kb = 0; kb < nkv; kb++) {
    const int kv0 = kb * 32;
    __syncthreads();
    {
      int r = tid >> 3, cc = (tid & 7) * 8;
      *(uint4*)&Kl[r * 64 + cc] = *(const uint4*)&kbase[(size_t)(kv0 + r) * 64 + cc];
      int rv = tid >> 2, cv = (tid & 3) * 8;
      *(uint4*)&Vl[rv * 32 + cv] = *(const uint4*)&vbase[(size_t)rv * 2048 + kv0 + cv];
    }
    __syncthreads();
    if (kv0 > wqmax) continue;  // fully masked for this wave (both barriers already passed)

    f32x4 s0 = {0.f, 0.f, 0.f, 0.f}, s1 = {0.f, 0.f, 0.f, 0.f};
#pragma unroll
    for (int c = 0; c < 2; c++) {
      bf16x8 qc = c ? qf1 : qf0;
      bf16x8 k0f = *(const bf16x8*)&Kl[lr * 64 + c * 32 + lg * 8];
      bf16x8 k1f = *(const bf16x8*)&Kl[(16 + lr) * 64 + c * 32 + lg * 8];
      s0 = __builtin_amdgcn_mfma_f32_16x16x32_bf16(qc, k0f, s0, 0, 0, 0);
      s1 = __builtin_amdgcn_mfma_f32_16x16x32_bf16(qc, k1f, s1, 0, 0, 0);
    }
    if (kv0 + 31 > wqmin) {  // diagonal block: elementwise causal mask
#pragma unroll
      for (int r = 0; r < 4; r++) {
        int rq = wqmin + lg * 4 + r;
        if (kv0 + lr > rq)      s0[r] = -3.0e38f;
        if (kv0 + 16 + lr > rq) s1[r] = -3.0e38f;
      }
    }
#pragma unroll
    for (int r = 0; r < 4; r++) {
      float mc = fmaxf(s0[r], s1[r]);
      mc = fmaxf(mc, __shfl_xor(mc, 1));
      mc = fmaxf(mc, __shfl_xor(mc, 2));
      mc = fmaxf(mc, __shfl_xor(mc, 4));
      mc = fmaxf(mc, __shfl_xor(mc, 8));
      float mnew = fmaxf(mrun[r], mc);
      float alpha = __expf(mrun[r] - mnew);
      mrun[r] = mnew;
      float p0 = __expf(s0[r] - mnew);
      float p1 = __expf(s1[r] - mnew);
      s0[r] = p0; s1[r] = p1;
      float ls = p0 + p1;
      ls += __shfl_xor(ls, 1);
      ls += __shfl_xor(ls, 2);
      ls += __shfl_xor(ls, 4);
      ls += __shfl_xor(ls, 8);
      lrun[r] = lrun[r] * alpha + ls;
      of[0][r] *= alpha; of[1][r] *= alpha; of[2][r] *= alpha; of[3][r] *= alpha;
    }
    // P (16x32) -> per-wave LDS, re-read as A-fragment layout
#pragma unroll
    for (int r = 0; r < 4; r++) {
      Pl[w][(lg * 4 + r) * 32 + lr]      = f2bf(s0[r]);
      Pl[w][(lg * 4 + r) * 32 + 16 + lr] = f2bf(s1[r]);
    }
    bf16x8 pa = *(const bf16x8*)&Pl[w][lr * 32 + lg * 8];
#pragma unroll
    for (int n = 0; n < 4; n++) {
      bf16x8 vf = *(const bf16x8*)&Vl[(n * 16 + lr) * 32 + lg * 8];
      of[n] = __builtin_amdgcn_mfma_f32_16x16x32_bf16(pa, vf, of[n], 0, 0, 0);
    }
  }
#pragma unroll
  for (int r = 0; r < 4; r++) lrun[r] = 1.0f / lrun[r];
#pragma unroll
  for (int n = 0; n < 4; n++)
#pragma unroll
    for (int r = 0; r < 4; r++) {
      int t = q0 + w * 16 + lg * 4 + r;
      att[(size_t)(b * 2048 + t) * 1024 + h * 64 + n * 16 + lr] = f2bf(of[n][r] * lrun[r]);
    }
}

extern "C" void kernel_launch(void* const* d_in, const int* in_sizes, int n_in,
                              void* d_out, int out_size, void* d_ws, size_t ws_size,
                              hipStream_t stream) {
  const float* x     = (const float*)d_in[0];
  const float* Wqkv  = (const float*)d_in[1];
  const float* Wproj = (const float*)d_in[2];
  float* out = (float*)d_out;

  char* ws = (char*)d_ws;
  size_t off = 0;
  auto alloc = [&](size_t bytes) { void* p = ws + off; off += (bytes + 255) & ~(size_t)255; return p; };
  unsigned short* xb   = (unsigned short*)alloc((size_t)4096 * 1024 * 2);
  unsigned short* wqt  = (unsigned short*)alloc((size_t)3072 * 1024 * 2);
  unsigned short* wpt  = (unsigned short*)alloc((size_t)1024 * 1024 * 2);
  unsigned short* qkvf = (unsigned short*)alloc((size_t)4096 * 3072 * 2);
  unsigned short* qh   = (unsigned short*)alloc((size_t)32 * 2048 * 64 * 2);
  unsigned short* kh   = (unsigned short*)alloc((size_t)32 * 2048 * 64 * 2);
  unsigned short* vt   = (unsigned short*)alloc((size_t)32 * 64 * 2048 * 2);
  unsigned short* att  = (unsigned short*)alloc((size_t)4096 * 1024 * 2);
  float* ctab = (float*)alloc((size_t)2048 * 32 * 4);
  float* stab = (float*)alloc((size_t)2048 * 32 * 4);

  k_convert<<<4096, 256, 0, stream>>>(x, xb, 4096 * 1024 / 4);
  k_wtrans<<<dim3(96, 32), dim3(32, 8), 0, stream>>>(Wqkv, wqt, 1024, 3072);
  k_wtrans<<<dim3(32, 32), dim3(32, 8), 0, stream>>>(Wproj, wpt, 1024, 1024);
  k_rope_tab<<<256, 256, 0, stream>>>(ctab, stab);
  k_gemm<1><<<dim3(24, 32), 256, 0, stream>>>(xb, wqt, qkvf, 4096, 3072, 1024);
  k_rope_split<<<16384, 256, 0, stream>>>(qkvf, ctab, stab, qh, kh);
  k_vtrans<<<dim3(32, 32), 256, 0, stream>>>(qkvf, vt);
  k_attn<<<dim3(32, 32), 256, 0, stream>>>(qh, kh, vt, att);
  k_gemm<0><<<dim3(8, 32), 256, 0, stream>>>(att, wpt, out, 4096, 1024, 1024);
}

// Round 2
// 139.585 us; speedup vs baseline: 1.9043x; 1.9043x over previous
//
#include <hip/hip_runtime.h>
#include <cstdint>
#include <cstddef>

typedef __attribute__((ext_vector_type(8))) short bf16x8;
typedef __attribute__((ext_vector_type(4))) float f32x4;

__device__ __forceinline__ unsigned short f2bf(float f) {
  unsigned int u = __builtin_bit_cast(unsigned int, f);
  u += 0x7FFFu + ((u >> 16) & 1u);
  return (unsigned short)(u >> 16);
}
__device__ __forceinline__ float bf2f(unsigned short h) {
  unsigned int u = ((unsigned int)h) << 16;
  return __builtin_bit_cast(float, u);
}

__device__ __forceinline__ void gl_lds16(const unsigned short* g, unsigned short* l) {
  __builtin_amdgcn_global_load_lds(
      (const __attribute__((address_space(1))) unsigned int*)(uintptr_t)g,
      (__attribute__((address_space(3))) unsigned int*)(unsigned int)(uintptr_t)l,
      16, 0, 0);
}

// ---------------- fp32 -> bf16 convert (x) ----------------
__global__ void k_convert(const float* __restrict__ in, unsigned short* __restrict__ out, int n4) {
  int i = blockIdx.x * blockDim.x + threadIdx.x;
  if (i >= n4) return;
  float4 v = reinterpret_cast<const float4*>(in)[i];
  uint2 o;
  o.x = (unsigned int)f2bf(v.x) | ((unsigned int)f2bf(v.y) << 16);
  o.y = (unsigned int)f2bf(v.z) | ((unsigned int)f2bf(v.w) << 16);
  reinterpret_cast<uint2*>(out)[i] = o;
}

// ---------------- transpose + convert W [K][N] fp32 -> [N][K] bf16 ----------------
__global__ void k_wtrans(const float* __restrict__ in, unsigned short* __restrict__ out,
                         int rows, int cols) {
  __shared__ float tile[32][33];
  int c0 = blockIdx.x * 32, r0 = blockIdx.y * 32;
  int tx = threadIdx.x, ty = threadIdx.y;
#pragma unroll
  for (int j = 0; j < 4; j++)
    tile[ty + j * 8][tx] = in[(size_t)(r0 + ty + j * 8) * cols + c0 + tx];
  __syncthreads();
#pragma unroll
  for (int j = 0; j < 4; j++)
    out[(size_t)(c0 + ty + j * 8) * rows + r0 + tx] = f2bf(tile[tx][ty + j * 8]);
}

// ---------------- RoPE cos/sin tables [2048][32] ----------------
__global__ void k_rope_tab(float* __restrict__ ct, float* __restrict__ st) {
  int i = blockIdx.x * blockDim.x + threadIdx.x;  // t*32 + j
  int t = i >> 5, j = i & 31;
  float invf = __powf(10000.0f, -(float)j / 32.0f);
  float ang = (float)t * invf;
  ct[i] = cosf(ang);
  st[i] = sinf(ang);
}

// ---------------- bf16 MFMA GEMM: C[M][N] = A[M][K] * Bt[N][K]^T ----------------
// 128x128 tile, BK=32, 4 waves (2x2), 4x4 16x16x32 frags per wave.
// Staging via global_load_lds width=16 (m97 recipe): linear LDS, lane-linear dest.
template<int OUT_BF16>
__global__ void k_gemm(const unsigned short* __restrict__ A,
                       const unsigned short* __restrict__ Bt,
                       void* __restrict__ C, int M, int N, int K) {
  __shared__ unsigned short Ta[128 * 32];
  __shared__ unsigned short Tb[128 * 32];
  const int tid = threadIdx.x;
  const int m0 = blockIdx.y * 128, n0 = blockIdx.x * 128;
  const int w = tid >> 6, l = tid & 63;
  const int lr = l & 15, lg = l >> 4;
  const int wm = (w >> 1) * 64, wn = (w & 1) * 64;
  // staging: wave w, inst i covers rows w*32+i*16 + l/4, cols (l&3)*8; LDS byte = w*2048 + i*1024 + l*16
  const int ssr = w * 32 + (l >> 2);
  const int ssc = (l & 3) * 8;
  unsigned short* ta0 = &Ta[w * 1024];
  unsigned short* tb0 = &Tb[w * 1024];
  f32x4 acc[4][4] = {};
  for (int k0 = 0; k0 < K; k0 += 32) {
    __syncthreads();
    gl_lds16(&A[(size_t)(m0 + ssr) * K + k0 + ssc],       ta0);
    gl_lds16(&A[(size_t)(m0 + ssr + 16) * K + k0 + ssc],  ta0 + 512);
    gl_lds16(&Bt[(size_t)(n0 + ssr) * K + k0 + ssc],      tb0);
    gl_lds16(&Bt[(size_t)(n0 + ssr + 16) * K + k0 + ssc], tb0 + 512);
    __syncthreads();
    bf16x8 af[4], bfr[4];
#pragma unroll
    for (int i = 0; i < 4; i++)
      af[i] = *(const bf16x8*)&Ta[(wm + i * 16 + lr) * 32 + lg * 8];
#pragma unroll
    for (int j = 0; j < 4; j++)
      bfr[j] = *(const bf16x8*)&Tb[(wn + j * 16 + lr) * 32 + lg * 8];
#pragma unroll
    for (int i = 0; i < 4; i++)
#pragma unroll
      for (int j = 0; j < 4; j++)
        acc[i][j] = __builtin_amdgcn_mfma_f32_16x16x32_bf16(af[i], bfr[j], acc[i][j], 0, 0, 0);
  }
#pragma unroll
  for (int i = 0; i < 4; i++)
#pragma unroll
    for (int j = 0; j < 4; j++)
#pragma unroll
      for (int r = 0; r < 4; r++) {
        int gm = m0 + wm + i * 16 + lg * 4 + r;
        int gn = n0 + wn + j * 16 + lr;
        float v = acc[i][j][r];
        if (OUT_BF16) ((unsigned short*)C)[(size_t)gm * N + gn] = f2bf(v);
        else          ((float*)C)[(size_t)gm * N + gn] = v;
      }
}

// ---------------- RoPE + split qkv -> qh (scaled 0.125*log2e), kh  [B,H,T,D] bf16 ----------
__global__ void k_rope_split(const unsigned short* __restrict__ qkv,
                             const float* __restrict__ ct, const float* __restrict__ st,
                             unsigned short* __restrict__ qh, unsigned short* __restrict__ kh) {
  int idx = blockIdx.x * blockDim.x + threadIdx.x;  // m*1024 + c
  int m = idx >> 10, c = idx & 1023;
  int t = m & 2047, b = m >> 11;
  int h = c >> 6, d = c & 63;
  int j = d & 31;
  float cs = ct[t * 32 + j], sn = st[t * 32 + j];
  size_t rowb = (size_t)m * 3072;
  float qv = bf2f(qkv[rowb + c]);
  float qo = bf2f(qkv[rowb + h * 64 + (d ^ 32)]);
  float kv = bf2f(qkv[rowb + 1024 + c]);
  float ko = bf2f(qkv[rowb + 1024 + h * 64 + (d ^ 32)]);
  float sgn = (d < 32) ? -1.0f : 1.0f;
  float qr = qv * cs + sgn * qo * sn;
  float kr = kv * cs + sgn * ko * sn;
  int bh = b * 16 + h;
  // fold softmax scale (1/8) and the exp->exp2 base change (log2 e) into Q
  qh[(size_t)(bh * 2048 + t) * 64 + d] = f2bf(qr * 0.180336880111120420f);
  kh[(size_t)(bh * 2048 + t) * 64 + d] = f2bf(kr);
}

// ---------------- V transpose: qkv v-part [m][c] -> vt [B,H,D,T] bf16 ----------------
__global__ void k_vtrans(const unsigned short* __restrict__ qkv, unsigned short* __restrict__ vt) {
  __shared__ unsigned short tile[64][72];
  const int bh = blockIdx.y, b = bh >> 4, h = bh & 15;
  const int t0 = blockIdx.x * 64;
  const int tid = threadIdx.x;
  {
    int r = tid >> 2, c = (tid & 3) * 16;
    const unsigned short* src = &qkv[(size_t)(b * 2048 + t0 + r) * 3072 + 2048 + h * 64 + c];
    uint4 v0 = *(const uint4*)src;
    uint4 v1 = *(const uint4*)(src + 8);
    *(uint4*)&tile[r][c] = v0;
    *(uint4*)&tile[r][c + 8] = v1;
  }
  __syncthreads();
#pragma unroll
  for (int q = 0; q < 2; q++) {
    int d = (tid >> 3) + q * 32;
    int tts = (tid & 7) * 8;
    unsigned short vals[8];
#pragma unroll
    for (int e = 0; e < 8; e++) vals[e] = tile[tts + e][d];
    *(uint4*)&vt[((size_t)bh * 64 + d) * 2048 + t0 + tts] = *(uint4*)vals;
  }
}

// ---------------- causal flash attention, swapped-QK^T form ----------------
// grid (16, B*H), 256 threads = 4 waves. Block handles q-tiles {bx, 31-bx} (64 rows each)
// sequentially -> every block does exactly 33 KV-64 steps (perfect balance).
// Wave w owns q rows [q0+16w, q0+16w+16); lane's q = q0+16w+(l&15) for softmax/O.
// S^T = mfma(K,Q): lane holds S[k=kv0+kq*16+lg*4+r][q]. Softmax: 15 reg-max + 2 shfl.
// P -> per-wave LDS [q][64k] (cvt_pk_bf16 + swizzled b64 writes), read back as B-frag.
// O^T = mfma(V^T, P^T): col=q matches softmax layout -> lane-local rescale.
// All 128B-row LDS tiles XOR-swizzled: byte ^= (row&7)<<4  (G4).
__global__ __launch_bounds__(256, 2) void k_attn(const unsigned short* __restrict__ qh,
                       const unsigned short* __restrict__ kh,
                       const unsigned short* __restrict__ vt,
                       unsigned short* __restrict__ att) {
  __shared__ unsigned short Kl[64 * 64];   // [k][d]
  __shared__ unsigned short Vl[64 * 64];   // [d][k]  (V^T)
  __shared__ unsigned short Pl[4][16 * 64];// per-wave [q][k]
  const int bh = blockIdx.y, b = bh >> 4, h = bh & 15;
  const int tid = threadIdx.x;
  const int w = tid >> 6, l = tid & 63;
  const int lr = l & 15, lg = l >> 4;
  const unsigned short* qbase = qh + (size_t)bh * 2048 * 64;
  const unsigned short* kbase = kh + (size_t)bh * 2048 * 64;
  const unsigned short* vbase = vt + (size_t)bh * 64 * 2048;
  char* KB = (char*)Kl;
  char* VB = (char*)Vl;
  char* PB = (char*)&Pl[w][0];
  const int swz = (lr & 7) << 4;
  // staging geometry: row sr (0..63), two 16B chunks at cols sc, sc+8
  const int sr = tid >> 2, sc = (tid & 3) * 16;
  const int sb0 = (sr * 128 + sc * 2) ^ ((sr & 7) << 4);
  const int sb1 = (sr * 128 + sc * 2 + 16) ^ ((sr & 7) << 4);

  for (int half = 0; half < 2; half++) {
    const int qt = half ? (31 - (int)blockIdx.x) : (int)blockIdx.x;
    const int q0 = qt * 64;
    const int wq = q0 + w * 16;
    const int qrow = wq + lr;                 // this lane's q (softmax/O layout)
    bf16x8 qf0 = *(const bf16x8*)&qbase[(size_t)qrow * 64 + lg * 8];
    bf16x8 qf1 = *(const bf16x8*)&qbase[(size_t)qrow * 64 + 32 + lg * 8];
    float mr = -3.0e38f, lsum = 0.0f;
    f32x4 of[4] = {};
    const int nkv = qt + 1;
    for (int kb = 0; kb < nkv; kb++) {
      const int kv0 = kb * 64;
      __syncthreads();
      {
        const unsigned short* ksrc = &kbase[(size_t)(kv0 + sr) * 64 + sc];
        const unsigned short* vsrc = &vbase[(size_t)sr * 2048 + kv0 + sc];
        uint4 ka = *(const uint4*)ksrc, kc4 = *(const uint4*)(ksrc + 8);
        uint4 va = *(const uint4*)vsrc, vc4 = *(const uint4*)(vsrc + 8);
        *(uint4*)(KB + sb0) = ka;  *(uint4*)(KB + sb1) = kc4;
        *(uint4*)(VB + sb0) = va;  *(uint4*)(VB + sb1) = vc4;
      }
      __syncthreads();
      // QK^T (swapped): s[kq] covers k rows kq*16.. , q cols
      f32x4 s[4] = {};
#pragma unroll
      for (int kq = 0; kq < 4; kq++) {
        bf16x8 kf0 = *(const bf16x8*)(KB + (((kq * 16 + lr) * 128 + lg * 16) ^ swz));
        bf16x8 kf1 = *(const bf16x8*)(KB + (((kq * 16 + lr) * 128 + 64 + lg * 16) ^ swz));
        s[kq] = __builtin_amdgcn_mfma_f32_16x16x32_bf16(kf0, qf0, s[kq], 0, 0, 0);
        s[kq] = __builtin_amdgcn_mfma_f32_16x16x32_bf16(kf1, qf1, s[kq], 0, 0, 0);
      }
      if (kb == qt) {  // diagonal block: causal mask
#pragma unroll
        for (int kq = 0; kq < 4; kq++)
#pragma unroll
          for (int r = 0; r < 4; r++)
            if (kv0 + kq * 16 + lg * 4 + r > qrow) s[kq][r] = -3.0e38f;
      }
      // online softmax (base-2 domain; scale folded into Q)
      float pm = s[0][0];
#pragma unroll
      for (int kq = 0; kq < 4; kq++)
#pragma unroll
        for (int r = 0; r < 4; r++) pm = fmaxf(pm, s[kq][r]);
      pm = fmaxf(pm, __shfl_xor(pm, 16));
      pm = fmaxf(pm, __shfl_xor(pm, 32));
      float mnew = fmaxf(mr, pm);
      float alpha = __builtin_amdgcn_exp2f(mr - mnew);
      mr = mnew;
      float psum = 0.0f;
#pragma unroll
      for (int kq = 0; kq < 4; kq++)
#pragma unroll
        for (int r = 0; r < 4; r++) {
          float p = __builtin_amdgcn_exp2f(s[kq][r] - mnew);
          s[kq][r] = p;
          psum += p;
        }
      psum += __shfl_xor(psum, 16);
      psum += __shfl_xor(psum, 32);
      lsum = lsum * alpha + psum;
#pragma unroll
      for (int n = 0; n < 4; n++) {
        of[n][0] *= alpha; of[n][1] *= alpha; of[n][2] *= alpha; of[n][3] *= alpha;
      }
      // P -> per-wave LDS [q][k] (wave-synchronous, no barrier needed)
#pragma unroll
      for (int kq = 0; kq < 4; kq++) {
        uint2 pk;
        asm("v_cvt_pk_bf16_f32 %0, %1, %2" : "=v"(pk.x) : "v"(s[kq][0]), "v"(s[kq][1]));
        asm("v_cvt_pk_bf16_f32 %0, %1, %2" : "=v"(pk.y) : "v"(s[kq][2]), "v"(s[kq][3]));
        *(uint2*)(PB + ((lr * 128 + (kq * 16 + lg * 4) * 2) ^ swz)) = pk;
      }
      bf16x8 pb0 = *(const bf16x8*)(PB + ((lr * 128 + lg * 16) ^ swz));
      bf16x8 pb1 = *(const bf16x8*)(PB + ((lr * 128 + 64 + lg * 16) ^ swz));
      // O^T += V^T * P^T
#pragma unroll
      for (int n = 0; n < 4; n++) {
        bf16x8 vf0 = *(const bf16x8*)(VB + (((n * 16 + lr) * 128 + lg * 16) ^ swz));
        bf16x8 vf1 = *(const bf16x8*)(VB + (((n * 16 + lr) * 128 + 64 + lg * 16) ^ swz));
        of[n] = __builtin_amdgcn_mfma_f32_16x16x32_bf16(vf0, pb0, of[n], 0, 0, 0);
        of[n] = __builtin_amdgcn_mfma_f32_16x16x32_bf16(vf1, pb1, of[n], 0, 0, 0);
      }
    }
    // normalize + store via per-wave LDS transpose (coalesced 128B rows)
    float inv = 1.0f / lsum;
#pragma unroll
    for (int n = 0; n < 4; n++) {
      uint2 pk;
      float o0 = of[n][0] * inv, o1 = of[n][1] * inv, o2 = of[n][2] * inv, o3 = of[n][3] * inv;
      asm("v_cvt_pk_bf16_f32 %0, %1, %2" : "=v"(pk.x) : "v"(o0), "v"(o1));
      asm("v_cvt_pk_bf16_f32 %0, %1, %2" : "=v"(pk.y) : "v"(o2), "v"(o3));
      *(uint2*)(PB + ((lr * 128 + (n * 16 + lg * 4) * 2) ^ swz)) = pk;
    }
    {
      int r2 = l >> 2, c2 = (l & 3) * 16;
      int bo0 = (r2 * 128 + c2 * 2) ^ ((r2 & 7) << 4);
      int bo1 = (r2 * 128 + c2 * 2 + 16) ^ ((r2 & 7) << 4);
      uint4 o0 = *(const uint4*)(PB + bo0);
      uint4 o1 = *(const uint4*)(PB + bo1);
      unsigned short* orow = att + (size_t)(b * 2048 + q0 + w * 16 + r2) * 1024 + h * 64 + c2;
      *(uint4*)orow = o0;
      *(uint4*)(orow + 8) = o1;
    }
  }
}

extern "C" void kernel_launch(void* const* d_in, const int* in_sizes, int n_in,
                              void* d_out, int out_size, void* d_ws, size_t ws_size,
                              hipStream_t stream) {
  const float* x     = (const float*)d_in[0];
  const float* Wqkv  = (const float*)d_in[1];
  const float* Wproj = (const float*)d_in[2];
  float* out = (float*)d_out;

  char* ws = (char*)d_ws;
  size_t off = 0;
  auto alloc = [&](size_t bytes) { void* p = ws + off; off += (bytes + 255) & ~(size_t)255; return p; };
  unsigned short* xb   = (unsigned short*)alloc((size_t)4096 * 1024 * 2);
  unsigned short* wqt  = (unsigned short*)alloc((size_t)3072 * 1024 * 2);
  unsigned short* wpt  = (unsigned short*)alloc((size_t)1024 * 1024 * 2);
  unsigned short* qkvf = (unsigned short*)alloc((size_t)4096 * 3072 * 2);
  unsigned short* qh   = (unsigned short*)alloc((size_t)32 * 2048 * 64 * 2);
  unsigned short* kh   = (unsigned short*)alloc((size_t)32 * 2048 * 64 * 2);
  unsigned short* vt   = (unsigned short*)alloc((size_t)32 * 64 * 2048 * 2);
  unsigned short* att  = (unsigned short*)alloc((size_t)4096 * 1024 * 2);
  float* ctab = (float*)alloc((size_t)2048 * 32 * 4);
  float* stab = (float*)alloc((size_t)2048 * 32 * 4);

  k_convert<<<4096, 256, 0, stream>>>(x, xb, 4096 * 1024 / 4);
  k_wtrans<<<dim3(96, 32), dim3(32, 8), 0, stream>>>(Wqkv, wqt, 1024, 3072);
  k_wtrans<<<dim3(32, 32), dim3(32, 8), 0, stream>>>(Wproj, wpt, 1024, 1024);
  k_rope_tab<<<256, 256, 0, stream>>>(ctab, stab);
  k_gemm<1><<<dim3(24, 32), 256, 0, stream>>>(xb, wqt, qkvf, 4096, 3072, 1024);
  k_rope_split<<<16384, 256, 0, stream>>>(qkvf, ctab, stab, qh, kh);
  k_vtrans<<<dim3(32, 32), 256, 0, stream>>>(qkvf, vt);
  k_attn<<<dim3(16, 32), 256, 0, stream>>>(qh, kh, vt, att);
  k_gemm<0><<<dim3(8, 32), 256, 0, stream>>>(att, wpt, out, 4096, 1024, 1024);
}

// Round 3
// 129.563 us; speedup vs baseline: 2.0516x; 1.0774x over previous
//
#include <hip/hip_runtime.h>
#include <cstdint>
#include <cstddef>

typedef __attribute__((ext_vector_type(8))) short bf16x8;
typedef __attribute__((ext_vector_type(4))) float f32x4;

__device__ __forceinline__ unsigned short f2bf(float f) {
  unsigned int u = __builtin_bit_cast(unsigned int, f);
  u += 0x7FFFu + ((u >> 16) & 1u);
  return (unsigned short)(u >> 16);
}
__device__ __forceinline__ float bf2f(unsigned short h) {
  unsigned int u = ((unsigned int)h) << 16;
  return __builtin_bit_cast(float, u);
}

__device__ __forceinline__ void gl_lds16(const unsigned short* g, unsigned short* l) {
  __builtin_amdgcn_global_load_lds(
      (const __attribute__((address_space(1))) unsigned int*)(uintptr_t)g,
      (__attribute__((address_space(3))) unsigned int*)(unsigned int)(uintptr_t)l,
      16, 0, 0);
}

// ---------------- fp32 -> bf16 convert (x) ----------------
__global__ void k_convert(const float* __restrict__ in, unsigned short* __restrict__ out, int n4) {
  int i = blockIdx.x * blockDim.x + threadIdx.x;
  if (i >= n4) return;
  float4 v = reinterpret_cast<const float4*>(in)[i];
  uint2 o;
  o.x = (unsigned int)f2bf(v.x) | ((unsigned int)f2bf(v.y) << 16);
  o.y = (unsigned int)f2bf(v.z) | ((unsigned int)f2bf(v.w) << 16);
  reinterpret_cast<uint2*>(out)[i] = o;
}

// ---------------- transpose + convert W [K][N] fp32 -> [N][K] bf16 ----------------
__global__ void k_wtrans(const float* __restrict__ in, unsigned short* __restrict__ out,
                         int rows, int cols) {
  __shared__ float tile[32][33];
  int c0 = blockIdx.x * 32, r0 = blockIdx.y * 32;
  int tx = threadIdx.x, ty = threadIdx.y;
#pragma unroll
  for (int j = 0; j < 4; j++)
    tile[ty + j * 8][tx] = in[(size_t)(r0 + ty + j * 8) * cols + c0 + tx];
  __syncthreads();
#pragma unroll
  for (int j = 0; j < 4; j++)
    out[(size_t)(c0 + ty + j * 8) * rows + r0 + tx] = f2bf(tile[tx][ty + j * 8]);
}

// ---------------- RoPE cos/sin tables [2048][32] ----------------
__global__ void k_rope_tab(float* __restrict__ ct, float* __restrict__ st) {
  int i = blockIdx.x * blockDim.x + threadIdx.x;  // t*32 + j
  int t = i >> 5, j = i & 31;
  float invf = __powf(10000.0f, -(float)j / 32.0f);
  float ang = (float)t * invf;
  ct[i] = cosf(ang);
  st[i] = sinf(ang);
}

// ---------------- bf16 MFMA GEMM: C[M][N] = A[M][K] * Bt[N][K]^T ----------------
// 128x128 tile, BK=32, 4 waves (2x2), 4x4 16x16x32 frags per wave. (m97 structure)
template<int OUT_BF16>
__global__ void k_gemm(const unsigned short* __restrict__ A,
                       const unsigned short* __restrict__ Bt,
                       void* __restrict__ C, int M, int N, int K) {
  __shared__ unsigned short Ta[128 * 32];
  __shared__ unsigned short Tb[128 * 32];
  const int tid = threadIdx.x;
  const int m0 = blockIdx.y * 128, n0 = blockIdx.x * 128;
  const int w = tid >> 6, l = tid & 63;
  const int lr = l & 15, lg = l >> 4;
  const int wm = (w >> 1) * 64, wn = (w & 1) * 64;
  const int ssr = w * 32 + (l >> 2);
  const int ssc = (l & 3) * 8;
  unsigned short* ta0 = &Ta[w * 1024];
  unsigned short* tb0 = &Tb[w * 1024];
  f32x4 acc[4][4] = {};
  for (int k0 = 0; k0 < K; k0 += 32) {
    __syncthreads();
    gl_lds16(&A[(size_t)(m0 + ssr) * K + k0 + ssc],       ta0);
    gl_lds16(&A[(size_t)(m0 + ssr + 16) * K + k0 + ssc],  ta0 + 512);
    gl_lds16(&Bt[(size_t)(n0 + ssr) * K + k0 + ssc],      tb0);
    gl_lds16(&Bt[(size_t)(n0 + ssr + 16) * K + k0 + ssc], tb0 + 512);
    __syncthreads();
    bf16x8 af[4], bfr[4];
#pragma unroll
    for (int i = 0; i < 4; i++)
      af[i] = *(const bf16x8*)&Ta[(wm + i * 16 + lr) * 32 + lg * 8];
#pragma unroll
    for (int j = 0; j < 4; j++)
      bfr[j] = *(const bf16x8*)&Tb[(wn + j * 16 + lr) * 32 + lg * 8];
#pragma unroll
    for (int i = 0; i < 4; i++)
#pragma unroll
      for (int j = 0; j < 4; j++)
        acc[i][j] = __builtin_amdgcn_mfma_f32_16x16x32_bf16(af[i], bfr[j], acc[i][j], 0, 0, 0);
  }
#pragma unroll
  for (int i = 0; i < 4; i++)
#pragma unroll
    for (int j = 0; j < 4; j++)
#pragma unroll
      for (int r = 0; r < 4; r++) {
        int gm = m0 + wm + i * 16 + lg * 4 + r;
        int gn = n0 + wn + j * 16 + lr;
        float v = acc[i][j][r];
        if (OUT_BF16) ((unsigned short*)C)[(size_t)gm * N + gn] = f2bf(v);
        else          ((float*)C)[(size_t)gm * N + gn] = v;
      }
}

// ---------------- RoPE + split qkv -> qh (scaled 0.125*log2e), kh  [B,H,T,D] bf16 ----------
__global__ void k_rope_split(const unsigned short* __restrict__ qkv,
                             const float* __restrict__ ct, const float* __restrict__ st,
                             unsigned short* __restrict__ qh, unsigned short* __restrict__ kh) {
  int idx = blockIdx.x * blockDim.x + threadIdx.x;  // m*1024 + c
  int m = idx >> 10, c = idx & 1023;
  int t = m & 2047, b = m >> 11;
  int h = c >> 6, d = c & 63;
  int j = d & 31;
  float cs = ct[t * 32 + j], sn = st[t * 32 + j];
  size_t rowb = (size_t)m * 3072;
  float qv = bf2f(qkv[rowb + c]);
  float qo = bf2f(qkv[rowb + h * 64 + (d ^ 32)]);
  float kv = bf2f(qkv[rowb + 1024 + c]);
  float ko = bf2f(qkv[rowb + 1024 + h * 64 + (d ^ 32)]);
  float sgn = (d < 32) ? -1.0f : 1.0f;
  float qr = qv * cs + sgn * qo * sn;
  float kr = kv * cs + sgn * ko * sn;
  int bh = b * 16 + h;
  // fold softmax scale (1/8) and the exp->exp2 base change (log2 e) into Q
  qh[(size_t)(bh * 2048 + t) * 64 + d] = f2bf(qr * 0.180336880111120420f);
  kh[(size_t)(bh * 2048 + t) * 64 + d] = f2bf(kr);
}

// ---------------- V transpose: qkv v-part [m][c] -> vt [B,H,D,T] bf16 ----------------
__global__ void k_vtrans(const unsigned short* __restrict__ qkv, unsigned short* __restrict__ vt) {
  __shared__ unsigned short tile[64][72];
  const int bh = blockIdx.y, b = bh >> 4, h = bh & 15;
  const int t0 = blockIdx.x * 64;
  const int tid = threadIdx.x;
  {
    int r = tid >> 2, c = (tid & 3) * 16;
    const unsigned short* src = &qkv[(size_t)(b * 2048 + t0 + r) * 3072 + 2048 + h * 64 + c];
    uint4 v0 = *(const uint4*)src;
    uint4 v1 = *(const uint4*)(src + 8);
    *(uint4*)&tile[r][c] = v0;
    *(uint4*)&tile[r][c + 8] = v1;
  }
  __syncthreads();
#pragma unroll
  for (int q = 0; q < 2; q++) {
    int d = (tid >> 3) + q * 32;
    int tts = (tid & 7) * 8;
    unsigned short vals[8];
#pragma unroll
    for (int e = 0; e < 8; e++) vals[e] = tile[tts + e][d];
    *(uint4*)&vt[((size_t)bh * 64 + d) * 2048 + t0 + tts] = *(uint4*)vals;
  }
}

// ---------------- causal flash attention, swapped-QK^T + async-stage + XCD swizzle ------
// 512 blocks, 256 threads = 4 waves. XCD-swizzled bid: xcd = bid&7 owns heads
// [4*xcd, 4*xcd+4) (K+V for 4 heads = 2MB -> L2-resident). Each block processes
// q-tile pair {qt0, 31-qt0} flattened into exactly 33 KV-64 steps; next step's K/V
// are issued global->reg during current step's compute (T14), LDS-written after the
// barrier. Both halves' online-softmax state lives in registers (static-indexed).
__global__ __launch_bounds__(256, 2) void k_attn(const unsigned short* __restrict__ qh,
                       const unsigned short* __restrict__ kh,
                       const unsigned short* __restrict__ vt,
                       unsigned short* __restrict__ att) {
  __shared__ unsigned short Kl[64 * 64];   // [k][d]
  __shared__ unsigned short Vl[64 * 64];   // [d][k]  (V^T)
  __shared__ unsigned short Pl[4][16 * 64];// per-wave [q][k]
  const int bid = blockIdx.x;
  const int bh  = ((bid & 7) << 2) | ((bid >> 3) >> 4);   // head-major per XCD
  const int qt0 = (bid >> 3) & 15;
  const int qt1 = 31 - qt0;
  const int b = bh >> 4, h = bh & 15;
  const int tid = threadIdx.x;
  const int w = tid >> 6, l = tid & 63;
  const int lr = l & 15, lg = l >> 4;
  const unsigned short* qbase = qh + (size_t)bh * 2048 * 64;
  const unsigned short* kbase = kh + (size_t)bh * 2048 * 64;
  const unsigned short* vbase = vt + (size_t)bh * 64 * 2048;
  char* KB = (char*)Kl;
  char* VB = (char*)Vl;
  char* PB = (char*)&Pl[w][0];
  const int swz = (lr & 7) << 4;
  const int sr = tid >> 2, sc = (tid & 3) * 16;
  const int sb0 = (sr * 128 + sc * 2) ^ ((sr & 7) << 4);
  const int sb1 = (sr * 128 + sc * 2 + 16) ^ ((sr & 7) << 4);

  const int q00 = qt0 * 64, q01 = qt1 * 64;
  const int qrow0 = q00 + w * 16 + lr;
  const int qrow1 = q01 + w * 16 + lr;
  bf16x8 qa0 = *(const bf16x8*)&qbase[(size_t)qrow0 * 64 + lg * 8];
  bf16x8 qb0 = *(const bf16x8*)&qbase[(size_t)qrow0 * 64 + 32 + lg * 8];
  bf16x8 qa1 = *(const bf16x8*)&qbase[(size_t)qrow1 * 64 + lg * 8];
  bf16x8 qb1 = *(const bf16x8*)&qbase[(size_t)qrow1 * 64 + 32 + lg * 8];

  float mr0 = -3.0e38f, ls0 = 0.0f;
  float mr1 = -3.0e38f, ls1 = 0.0f;
  f32x4 of0[4] = {}, of1[4] = {};
  uint4 ka0, ka1, va0, va1;   // in-flight K/V tile (T14)

  auto issue = [&](int kv0) {
    const unsigned short* ksrc = &kbase[(size_t)(kv0 + sr) * 64 + sc];
    const unsigned short* vsrc = &vbase[(size_t)sr * 2048 + kv0 + sc];
    ka0 = *(const uint4*)ksrc; ka1 = *(const uint4*)(ksrc + 8);
    va0 = *(const uint4*)vsrc; va1 = *(const uint4*)(vsrc + 8);
  };

  auto step = [&](f32x4 (&of)[4], float& mr, float& ls, bf16x8 qa, bf16x8 qb,
                  int qrow, int kv0, bool diag) {
    f32x4 s[4] = {};
    __builtin_amdgcn_s_setprio(1);
#pragma unroll
    for (int kq = 0; kq < 4; kq++) {
      bf16x8 kf0 = *(const bf16x8*)(KB + (((kq * 16 + lr) * 128 + lg * 16) ^ swz));
      bf16x8 kf1 = *(const bf16x8*)(KB + (((kq * 16 + lr) * 128 + 64 + lg * 16) ^ swz));
      s[kq] = __builtin_amdgcn_mfma_f32_16x16x32_bf16(kf0, qa, s[kq], 0, 0, 0);
      s[kq] = __builtin_amdgcn_mfma_f32_16x16x32_bf16(kf1, qb, s[kq], 0, 0, 0);
    }
    __builtin_amdgcn_s_setprio(0);
    if (diag) {
#pragma unroll
      for (int kq = 0; kq < 4; kq++)
#pragma unroll
        for (int r = 0; r < 4; r++)
          if (kv0 + kq * 16 + lg * 4 + r > qrow) s[kq][r] = -3.0e38f;
    }
    float pm = s[0][0];
#pragma unroll
    for (int kq = 0; kq < 4; kq++)
#pragma unroll
      for (int r = 0; r < 4; r++) pm = fmaxf(pm, s[kq][r]);
    pm = fmaxf(pm, __shfl_xor(pm, 16));
    pm = fmaxf(pm, __shfl_xor(pm, 32));
    float mnew = fmaxf(mr, pm);
    float alpha = __builtin_amdgcn_exp2f(mr - mnew);
    mr = mnew;
    float psum = 0.0f;
#pragma unroll
    for (int kq = 0; kq < 4; kq++)
#pragma unroll
      for (int r = 0; r < 4; r++) {
        float p = __builtin_amdgcn_exp2f(s[kq][r] - mnew);
        s[kq][r] = p;
        psum += p;
      }
    psum += __shfl_xor(psum, 16);
    psum += __shfl_xor(psum, 32);
    ls = ls * alpha + psum;
#pragma unroll
    for (int n = 0; n < 4; n++) {
      of[n][0] *= alpha; of[n][1] *= alpha; of[n][2] *= alpha; of[n][3] *= alpha;
    }
    // P -> per-wave LDS [q][k] (wave-synchronous)
#pragma unroll
    for (int kq = 0; kq < 4; kq++) {
      uint2 pk;
      asm("v_cvt_pk_bf16_f32 %0, %1, %2" : "=v"(pk.x) : "v"(s[kq][0]), "v"(s[kq][1]));
      asm("v_cvt_pk_bf16_f32 %0, %1, %2" : "=v"(pk.y) : "v"(s[kq][2]), "v"(s[kq][3]));
      *(uint2*)(PB + ((lr * 128 + (kq * 16 + lg * 4) * 2) ^ swz)) = pk;
    }
    bf16x8 pb0 = *(const bf16x8*)(PB + ((lr * 128 + lg * 16) ^ swz));
    bf16x8 pb1 = *(const bf16x8*)(PB + ((lr * 128 + 64 + lg * 16) ^ swz));
    __builtin_amdgcn_s_setprio(1);
#pragma unroll
    for (int n = 0; n < 4; n++) {
      bf16x8 vf0 = *(const bf16x8*)(VB + (((n * 16 + lr) * 128 + lg * 16) ^ swz));
      bf16x8 vf1 = *(const bf16x8*)(VB + (((n * 16 + lr) * 128 + 64 + lg * 16) ^ swz));
      of[n] = __builtin_amdgcn_mfma_f32_16x16x32_bf16(vf0, pb0, of[n], 0, 0, 0);
      of[n] = __builtin_amdgcn_mfma_f32_16x16x32_bf16(vf1, pb1, of[n], 0, 0, 0);
    }
    __builtin_amdgcn_s_setprio(0);
  };

  issue(0);
  const int nkv0 = qt0 + 1;
  for (int s2 = 0; s2 < 33; s2++) {
    __syncthreads();
    // stage in-flight regs -> LDS (compiler inserts the vmcnt wait here)
    *(uint4*)(KB + sb0) = ka0;  *(uint4*)(KB + sb1) = ka1;
    *(uint4*)(VB + sb0) = va0;  *(uint4*)(VB + sb1) = va1;
    __syncthreads();
    if (s2 < 32) {               // T14: issue next tile during this step's compute
      int ns = s2 + 1;
      issue(((ns < nkv0) ? ns : ns - nkv0) * 64);
    }
    if (s2 < nkv0) step(of0, mr0, ls0, qa0, qb0, qrow0, s2 * 64, s2 == qt0);
    else           step(of1, mr1, ls1, qa1, qb1, qrow1, (s2 - nkv0) * 64, s2 == 32);
  }

  auto store_half = [&](f32x4 (&of)[4], float ls, int q0) {
    float inv = 1.0f / ls;
#pragma unroll
    for (int n = 0; n < 4; n++) {
      uint2 pk;
      float o0 = of[n][0] * inv, o1 = of[n][1] * inv, o2 = of[n][2] * inv, o3 = of[n][3] * inv;
      asm("v_cvt_pk_bf16_f32 %0, %1, %2" : "=v"(pk.x) : "v"(o0), "v"(o1));
      asm("v_cvt_pk_bf16_f32 %0, %1, %2" : "=v"(pk.y) : "v"(o2), "v"(o3));
      *(uint2*)(PB + ((lr * 128 + (n * 16 + lg * 4) * 2) ^ swz)) = pk;
    }
    int r2 = l >> 2, c2 = (l & 3) * 16;
    int bo0 = (r2 * 128 + c2 * 2) ^ ((r2 & 7) << 4);
    int bo1 = (r2 * 128 + c2 * 2 + 16) ^ ((r2 & 7) << 4);
    uint4 o0 = *(const uint4*)(PB + bo0);
    uint4 o1 = *(const uint4*)(PB + bo1);
    unsigned short* orow = att + (size_t)(b * 2048 + q0 + w * 16 + r2) * 1024 + h * 64 + c2;
    *(uint4*)orow = o0;
    *(uint4*)(orow + 8) = o1;
  };
  store_half(of0, ls0, q00);
  store_half(of1, ls1, q01);
}

extern "C" void kernel_launch(void* const* d_in, const int* in_sizes, int n_in,
                              void* d_out, int out_size, void* d_ws, size_t ws_size,
                              hipStream_t stream) {
  const float* x     = (const float*)d_in[0];
  const float* Wqkv  = (const float*)d_in[1];
  const float* Wproj = (const float*)d_in[2];
  float* out = (float*)d_out;

  char* ws = (char*)d_ws;
  size_t off = 0;
  auto alloc = [&](size_t bytes) { void* p = ws + off; off += (bytes + 255) & ~(size_t)255; return p; };
  unsigned short* xb   = (unsigned short*)alloc((size_t)4096 * 1024 * 2);
  unsigned short* wqt  = (unsigned short*)alloc((size_t)3072 * 1024 * 2);
  unsigned short* wpt  = (unsigned short*)alloc((size_t)1024 * 1024 * 2);
  unsigned short* qkvf = (unsigned short*)alloc((size_t)4096 * 3072 * 2);
  unsigned short* qh   = (unsigned short*)alloc((size_t)32 * 2048 * 64 * 2);
  unsigned short* kh   = (unsigned short*)alloc((size_t)32 * 2048 * 64 * 2);
  unsigned short* vt   = (unsigned short*)alloc((size_t)32 * 64 * 2048 * 2);
  unsigned short* att  = (unsigned short*)alloc((size_t)4096 * 1024 * 2);
  float* ctab = (float*)alloc((size_t)2048 * 32 * 4);
  float* stab = (float*)alloc((size_t)2048 * 32 * 4);

  k_convert<<<4096, 256, 0, stream>>>(x, xb, 4096 * 1024 / 4);
  k_wtrans<<<dim3(96, 32), dim3(32, 8), 0, stream>>>(Wqkv, wqt, 1024, 3072);
  k_wtrans<<<dim3(32, 32), dim3(32, 8), 0, stream>>>(Wproj, wpt, 1024, 1024);
  k_rope_tab<<<256, 256, 0, stream>>>(ctab, stab);
  k_gemm<1><<<dim3(24, 32), 256, 0, stream>>>(xb, wqt, qkvf, 4096, 3072, 1024);
  k_rope_split<<<16384, 256, 0, stream>>>(qkvf, ctab, stab, qh, kh);
  k_vtrans<<<dim3(32, 32), 256, 0, stream>>>(qkvf, vt);
  k_attn<<<512, 256, 0, stream>>>(qh, kh, vt, att);
  k_gemm<0><<<dim3(8, 32), 256, 0, stream>>>(att, wpt, out, 4096, 1024, 1024);
}